// Round 6
// baseline (386.428 us; speedup 1.0000x reference)
//
#include <hip/hip_runtime.h>
#include <hip/hip_bf16.h>
#include <stdint.h>

// ---------- types ----------
typedef __attribute__((ext_vector_type(8))) short bf8_t;    // 8 bf16 (4 VGPRs)
typedef __attribute__((ext_vector_type(4))) float f32x4_t;
typedef __attribute__((ext_vector_type(4))) unsigned short us4_t;

#define MFMA_BF16 __builtin_amdgcn_mfma_f32_16x16x32_bf16

__device__ __forceinline__ unsigned short f2bf(float f) {
  union { float f; unsigned u; } x; x.f = f;
  unsigned r = (x.u + 0x7FFFu + ((x.u >> 16) & 1u)) >> 16;
  return (unsigned short)r;
}
__device__ __forceinline__ float bf2f(unsigned short b) {
  union { unsigned u; float f; } x; x.u = ((unsigned)b) << 16;
  return x.f;
}

// Bijective XCD-chunked swizzle (m204): each XCD owns a contiguous slab of
// node-blocks -> neighbor gathers hit the same XCD's (non-coherent) L2.
__device__ __forceinline__ int xcd_swizzle(int b, int nwg) {
  const int NX = 8;
  int q = nwg / NX, r = nwg % NX;
  int xcd = b % NX, idx = b / NX;
  int start = (xcd < r) ? xcd * (q + 1) : r * (q + 1) + (xcd - r) * q;
  return start + idx;
}

// ---------- evolution-row scalars: w0, w1 per layer ----------
// A = star K_{1,deg}; G=expm(-iAt) acts as [[cos(rt),-i sin(rt)],[-i sin(rt),cos(rt)]]
// on span{e0,u'}, identity elsewhere; r = sqrt(deg).
__global__ void compute_wscal(const float* t1r, const float* t1i,
                              const float* t2r, const float* t2i,
                              float* wsc, int deg) {
  if (threadIdx.x != 0 || blockIdx.x != 0) return;
  float r = sqrtf((float)deg);
  for (int l = 0; l < 2; ++l) {
    float tr = l ? t2r[0] : t1r[0];
    float ti = l ? t2i[0] : t1i[0];
    float x = r * tr, y = r * ti;
    float cr = cosf(x) * coshf(y), ci = -sinf(x) * sinhf(y);
    float sr = sinf(x) * coshf(y), si = cosf(x) * sinhf(y);
    float a = cr * cr + ci * ci + sr * sr + si * si;
    float b = -2.0f * (ci * sr - cr * si);
    float s2 = fmaxf(a + fabsf(b), 1.0f);
    float s = sqrtf(s2);
    float l0r = cr / s, l0i = ci / s;              // Lt[0,0]
    float l1r = si / (r * s), l1i = -sr / (r * s); // Lt[0,j]
    float q0 = 1.0f - a / s2;                      // Rt[0,0]^2 (real)
    float r0r = (q0 >= 0.0f) ? sqrtf(q0) : 0.0f;
    float r0i = (q0 >= 0.0f) ? 0.0f : sqrtf(-q0);
    float q1 = -b / (r * s2);                      // Rt[0,j]^2 (real)
    float r1r = (q1 >= 0.0f) ? sqrtf(q1) : 0.0f;
    float r1i = (q1 >= 0.0f) ? 0.0f : sqrtf(-q1);
    wsc[l * 4 + 0] = l0r + r0r;  // w0.re
    wsc[l * 4 + 1] = l0i + r0i;  // w0.im
    wsc[l * 4 + 2] = l1r + r1r;  // w1.re (same for all neighbors)
    wsc[l * 4 + 3] = l1i + r1i;  // w1.im
  }
}

// ---------- neighbor-list build: wave-cooperative, one atomic per key-group ----
__device__ __forceinline__ void store_side(int* __restrict__ cnt,
                                           int* __restrict__ nbrs,
                                           int deg, int key, int val) {
  unsigned long long remaining = __ballot(1);
  unsigned long long mymask = 0;
  while (remaining) {
    int lead = __ffsll((long long)remaining) - 1;
    int lkey = __shfl(key, lead);
    unsigned long long m = __ballot(key == lkey);
    if (key == lkey) mymask = m;
    remaining &= ~m;
  }
  const int lane = threadIdx.x & 63;
  const int leader = __ffsll((long long)mymask) - 1;
  int base = 0;
  if (lane == leader) base = atomicAdd(&cnt[key], __popcll(mymask));
  base = __shfl(base, leader);
  const int rank = __popcll(mymask & ((1ull << lane) - 1ull));
  nbrs[(long)key * deg + base + rank] = val;
}

__global__ __launch_bounds__(256) void build_nbrs(
    const int* __restrict__ ei, int E, int* __restrict__ cnt,
    int* __restrict__ nbrs, int deg) {
  int e = blockIdx.x * 256 + threadIdx.x;
  if (e >= E) return;
  int s = ei[e], d = ei[E + e];
  store_side(cnt, nbrs, deg, s, d);
  store_side(cnt, nbrs, deg, d, s);
}

// ---------- single-plane W staging: f32 global -> bf16 swizzled LDS (32 KB) ----
// byte ^= ((c&7)<<4) breaks the stride-256B bank conflict on ds_read_b128.
__device__ __forceinline__ void stage_w_plane(unsigned char* ldsW,
                                              const float* __restrict__ src,
                                              int tid) {
#pragma unroll
  for (int i = 0; i < 4; ++i) {
    const int e8 = (i * 512 + tid) * 8;             // 8 consecutive f32
    float4 a = *(const float4*)(src + e8);
    float4 b = *(const float4*)(src + e8 + 4);
    union { bf8_t v; unsigned short s[8]; } o;
    o.s[0] = f2bf(a.x); o.s[1] = f2bf(a.y); o.s[2] = f2bf(a.z); o.s[3] = f2bf(a.w);
    o.s[4] = f2bf(b.x); o.s[5] = f2bf(b.y); o.s[6] = f2bf(b.z); o.s[7] = f2bf(b.w);
    const int c = e8 >> 7, k = e8 & 127;
    const int byte = c * 256 + ((k * 2) ^ ((c & 7) << 4));
    *(bf8_t*)(ldsW + byte) = o.v;
  }
}

// Interleaved hidden-state layout: per node 256 us (512 B):
//   chunk g in [0,16): elems [g*16 .. +7] = re[g*8..+7], [g*16+8 .. +15] = im.

// ---------- layer-1 GEMM: h1 = crelu(x @ W1^T + b1), real f32 input ----------
// Two W-plane passes over 32 KB LDS -> small LDS block, high occupancy.
__global__ __launch_bounds__(512, 4) void gemm_l1(
    const float* __restrict__ Xf,
    const float* __restrict__ Wr, const float* __restrict__ Wi,
    const float* __restrict__ br, const float* __restrict__ bi,
    unsigned short* __restrict__ H1, int n) {
  __shared__ unsigned char ldsW[32768];
  const int tid = threadIdx.x;
  const int wv = tid >> 6, lane = tid & 63;
  const int fr = lane & 15, kg = lane >> 4;
  const int lb = xcd_swizzle(blockIdx.x, gridDim.x);
  const int rowbase = lb * 128 + wv * 16;
  const int node = min(rowbase + fr, n - 1);
  const long a_off = (long)node * 128;

  stage_w_plane(ldsW, Wr, tid);                     // pass 1: Wr

  bf8_t a[4];
#pragma unroll
  for (int ks = 0; ks < 4; ++ks) {
    const int koff = ks * 32 + kg * 8;
    float4 u = *(const float4*)(Xf + a_off + koff);
    float4 v = *(const float4*)(Xf + a_off + koff + 4);
    union { bf8_t vv; unsigned short s[8]; } t;
    t.s[0] = f2bf(u.x); t.s[1] = f2bf(u.y); t.s[2] = f2bf(u.z); t.s[3] = f2bf(u.w);
    t.s[4] = f2bf(v.x); t.s[5] = f2bf(v.y); t.s[6] = f2bf(v.z); t.s[7] = f2bf(v.w);
    a[ks] = t.vv;
  }
  __syncthreads();

  f32x4_t accr[8], acci[8];
#pragma unroll
  for (int i = 0; i < 8; ++i) { accr[i] = (f32x4_t)0.0f; acci[i] = (f32x4_t)0.0f; }

#pragma unroll
  for (int cf = 0; cf < 8; ++cf) {
    const int c = cf * 16 + fr;
    const int cbyte = c * 256, swz = (c & 7) << 4;
#pragma unroll
    for (int ks = 0; ks < 4; ++ks) {
      const int kb = (ks * 32 + kg * 8) * 2;
      bf8_t w = *(const bf8_t*)(ldsW + cbyte + (kb ^ swz));
      accr[cf] = MFMA_BF16(w, a[ks], accr[cf], 0, 0, 0);
    }
  }
  __syncthreads();
  stage_w_plane(ldsW, Wi, tid);                     // pass 2: Wi
  __syncthreads();
#pragma unroll
  for (int cf = 0; cf < 8; ++cf) {
    const int c = cf * 16 + fr;
    const int cbyte = c * 256, swz = (c & 7) << 4;
#pragma unroll
    for (int ks = 0; ks < 4; ++ks) {
      const int kb = (ks * 32 + kg * 8) * 2;
      bf8_t w = *(const bf8_t*)(ldsW + cbyte + (kb ^ swz));
      acci[cf] = MFMA_BF16(w, a[ks], acci[cf], 0, 0, 0);
    }
  }

  const int onode = rowbase + fr;
  if (onode < n) {
    const long obase = (long)onode * 256;
#pragma unroll
    for (int cf = 0; cf < 8; ++cf) {
      const int cb = cf * 16 + kg * 4;
      const int chunk = cb >> 3, sub = cb & 7;
      union { float4 f4; float f[4]; } b4r, b4i;
      b4r.f4 = *(const float4*)(br + cb);
      b4i.f4 = *(const float4*)(bi + cb);
      us4_t pr, pi;
#pragma unroll
      for (int j = 0; j < 4; ++j) {
        pr[j] = f2bf(fmaxf(accr[cf][j] + b4r.f[j], 0.0f));
        pi[j] = f2bf(fmaxf(acci[cf][j] + b4i.f[j], 0.0f));
      }
      *(us4_t*)(H1 + obase + chunk * 16 + sub) = pr;
      *(us4_t*)(H1 + obase + chunk * 16 + 8 + sub) = pi;
    }
  }
}

// ---------- fused layer-1 aggregation + layer-2 GEMM + crelu ----------
// g = w0*h1 + w1*sum_nbr(h1) + eb1 (f32) -> bf16 A-fragments in registers,
// then h2 = crelu(g @ W2^T + b2). Two W-plane passes; nb list in LDS (pad 17).
template <int DEG>
__global__ __launch_bounds__(512, 4) void fused_l2(
    const unsigned short* __restrict__ H1,
    const int* __restrict__ nbrs, const float* __restrict__ wsc,
    const float* __restrict__ eb1r, const float* __restrict__ eb1i,
    const float* __restrict__ W2r, const float* __restrict__ W2i,
    const float* __restrict__ b2r, const float* __restrict__ b2i,
    unsigned short* __restrict__ H2, int n, int deg_rt) {
  __shared__ unsigned char ldsW[32768];
  __shared__ int ldsNB[128 * 17];                   // pad 17: conflict-free bcast
  const int tid = threadIdx.x;
  const int wv = tid >> 6, lane = tid & 63;
  const int fr = lane & 15, kg = lane >> 4;
  const int lb = xcd_swizzle(blockIdx.x, gridDim.x);
  const int rowbase = lb * 128 + wv * 16;
  const int node = min(rowbase + fr, n - 1);
  const int nloc = wv * 16 + fr;                    // block-local node idx
  const float w0r = wsc[0], w0i = wsc[1], w1r = wsc[2], w1i = wsc[3];
  const int deg = DEG ? DEG : deg_rt;

  // stage nb lists for the block's 128 nodes, coalesced; clamp to [0,n-1]
  {
    const long base = (long)lb * 128 * deg;
    const long lim = (long)n * deg;
    for (int i = tid; i < 128 * deg; i += 512) {
      long gidx = base + i;
      int v = (gidx < lim) ? nbrs[gidx] : 0;
      v = min(max(v, 0), n - 1);
      ldsNB[(i / deg) * 17 + (i % deg)] = v;
    }
  }
  stage_w_plane(ldsW, W2r, tid);                    // pass 1: Wr
  __syncthreads();

  // ---- gather + aggregate -> bf16 A-fragments (gr in ar[], gi in ai[]) ----
  bf8_t ar[4], ai[4];
#pragma unroll
  for (int ks = 0; ks < 4; ++ks) {
    const int ch16 = (ks * 4 + kg) * 16;            // interleaved chunk offset
    union { bf8_t v; unsigned short s[8]; } o_r, o_i;
    o_r.v = *(const bf8_t*)(H1 + (long)node * 256 + ch16);
    o_i.v = *(const bf8_t*)(H1 + (long)node * 256 + ch16 + 8);
    float sr[8], si[8];
#pragma unroll
    for (int e = 0; e < 8; ++e) { sr[e] = 0.0f; si[e] = 0.0f; }
#pragma unroll
    for (int j = 0; j < (DEG ? DEG : 1); ++j) {
      for (int jj = DEG ? j : 0; jj < (DEG ? j + 1 : deg); ++jj) {
        const long m = (long)ldsNB[nloc * 17 + jj] * 256 + ch16;
        union { bf8_t v; unsigned short s[8]; } vr2, vi2;
        vr2.v = *(const bf8_t*)(H1 + m);
        vi2.v = *(const bf8_t*)(H1 + m + 8);
#pragma unroll
        for (int e = 0; e < 8; ++e) { sr[e] += bf2f(vr2.s[e]); si[e] += bf2f(vi2.s[e]); }
      }
    }
    const int koff = ks * 32 + kg * 8;
    union { float4 f4; float f[4]; } er0, er1, ei0, ei1;
    er0.f4 = *(const float4*)(eb1r + koff);
    er1.f4 = *(const float4*)(eb1r + koff + 4);
    ei0.f4 = *(const float4*)(eb1i + koff);
    ei1.f4 = *(const float4*)(eb1i + koff + 4);
    union { bf8_t v; unsigned short s[8]; } pr, pi;
#pragma unroll
    for (int e = 0; e < 8; ++e) {
      float hr = bf2f(o_r.s[e]), hi = bf2f(o_i.s[e]);
      float ebR = (e < 4) ? er0.f[e] : er1.f[e - 4];
      float ebI = (e < 4) ? ei0.f[e] : ei1.f[e - 4];
      float gr = w0r * hr - w0i * hi + w1r * sr[e] - w1i * si[e] + ebR;
      float gi = w0r * hi + w0i * hr + w1r * si[e] + w1i * sr[e] + ebI;
      pr.s[e] = f2bf(gr); pi.s[e] = f2bf(gi);
    }
    ar[ks] = pr.v; ai[ks] = pi.v;
  }

  f32x4_t accr[8], acci[8];
#pragma unroll
  for (int i = 0; i < 8; ++i) { accr[i] = (f32x4_t)0.0f; acci[i] = (f32x4_t)0.0f; }

  // pass 1 (Wr): accr += Wr*gr ; acci += Wr*gi
#pragma unroll
  for (int cf = 0; cf < 8; ++cf) {
    const int c = cf * 16 + fr;
    const int cbyte = c * 256, swz = (c & 7) << 4;
#pragma unroll
    for (int ks = 0; ks < 4; ++ks) {
      const int kb = (ks * 32 + kg * 8) * 2;
      bf8_t w = *(const bf8_t*)(ldsW + cbyte + (kb ^ swz));
      accr[cf] = MFMA_BF16(w, ar[ks], accr[cf], 0, 0, 0);
      acci[cf] = MFMA_BF16(w, ai[ks], acci[cf], 0, 0, 0);
    }
  }
  __syncthreads();
  stage_w_plane(ldsW, W2i, tid);                    // pass 2: Wi
  __syncthreads();

  // negate gi in place: ain = -gi
#pragma unroll
  for (int ks = 0; ks < 4; ++ks) {
    union { bf8_t v; unsigned u[4]; } t; t.v = ai[ks];
#pragma unroll
    for (int q = 0; q < 4; ++q) t.u[q] ^= 0x80008000u;
    ai[ks] = t.v;
  }
  // pass 2 (Wi): accr += Wi*(-gi) ; acci += Wi*gr
#pragma unroll
  for (int cf = 0; cf < 8; ++cf) {
    const int c = cf * 16 + fr;
    const int cbyte = c * 256, swz = (c & 7) << 4;
#pragma unroll
    for (int ks = 0; ks < 4; ++ks) {
      const int kb = (ks * 32 + kg * 8) * 2;
      bf8_t w = *(const bf8_t*)(ldsW + cbyte + (kb ^ swz));
      accr[cf] = MFMA_BF16(w, ai[ks], accr[cf], 0, 0, 0);
      acci[cf] = MFMA_BF16(w, ar[ks], acci[cf], 0, 0, 0);
    }
  }

  const int onode = rowbase + fr;
  if (onode < n) {
    const long obase = (long)onode * 256;
#pragma unroll
    for (int cf = 0; cf < 8; ++cf) {
      const int cb = cf * 16 + kg * 4;
      const int chunk = cb >> 3, sub = cb & 7;
      union { float4 f4; float f[4]; } b4r, b4i;
      b4r.f4 = *(const float4*)(b2r + cb);
      b4i.f4 = *(const float4*)(b2i + cb);
      us4_t pr, pi;
#pragma unroll
      for (int j = 0; j < 4; ++j) {
        pr[j] = f2bf(fmaxf(accr[cf][j] + b4r.f[j], 0.0f));
        pi[j] = f2bf(fmaxf(acci[cf][j] + b4i.f[j], 0.0f));
      }
      *(us4_t*)(H2 + obase + chunk * 16 + sub) = pr;
      *(us4_t*)(H2 + obase + chunk * 16 + 8 + sub) = pi;
    }
  }
}

// ---------- final aggregation: out = Re(w0*h + w1*sum_nbr(h) + eb) -------------
template <int DEG>
__global__ __launch_bounds__(256) void agg_final(
    const unsigned short* __restrict__ H2,
    const int* __restrict__ nbrs, const float* __restrict__ wsc,
    const float* __restrict__ ebr,
    float* __restrict__ outf, int n, int deg_rt) {
  const int lb = xcd_swizzle(blockIdx.x, gridDim.x);
  const int g = lb * 256 + threadIdx.x;
  const int node = g >> 4;
  if (node >= n) return;
  const int g2 = g & 15;                 // chunk index
  const int ch0 = g2 * 8;
  const int deg = DEG ? DEG : deg_rt;
  const float w0r = wsc[0], w0i = wsc[1], w1r = wsc[2], w1i = wsc[3];

  union { bf8_t v; unsigned short s[8]; } ur, ui;
  ur.v = *(const bf8_t*)(H2 + (long)node * 256 + g2 * 16);
  ui.v = *(const bf8_t*)(H2 + (long)node * 256 + g2 * 16 + 8);
  float srf[8], sif[8];
#pragma unroll
  for (int e = 0; e < 8; ++e) { srf[e] = 0.0f; sif[e] = 0.0f; }
  const int* nbp = nbrs + (long)node * deg;
#pragma unroll
  for (int k = 0; k < (DEG ? DEG : 1); ++k) {
    for (int kk = DEG ? k : 0; kk < (DEG ? k + 1 : deg); ++kk) {
      const long m = (long)nbp[kk] * 256 + g2 * 16;
      union { bf8_t v; unsigned short s[8]; } vr2, vi2;
      vr2.v = *(const bf8_t*)(H2 + m);
      vi2.v = *(const bf8_t*)(H2 + m + 8);
#pragma unroll
      for (int e = 0; e < 8; ++e) { srf[e] += bf2f(vr2.s[e]); sif[e] += bf2f(vi2.s[e]); }
    }
  }
  union { float4 f4; float f[4]; } o0, o1;
#pragma unroll
  for (int e = 0; e < 8; ++e) {
    const int c = ch0 + e;
    float hrf = bf2f(ur.s[e]), hif = bf2f(ui.s[e]);
    float R = w0r * hrf - w0i * hif + w1r * srf[e] - w1i * sif[e] + ebr[c];
    if (e < 4) o0.f[e] = R; else o1.f[e - 4] = R;
  }
  *(float4*)(outf + (long)node * 128 + ch0) = o0.f4;
  *(float4*)(outf + (long)node * 128 + ch0 + 4) = o1.f4;
}

// ---------- launch ----------
extern "C" void kernel_launch(void* const* d_in, const int* in_sizes, int n_in,
                              void* d_out, int out_size, void* d_ws, size_t ws_size,
                              hipStream_t stream) {
  const float* x    = (const float*)d_in[0];
  const int*   ei   = (const int*)d_in[1];
  const float* W1r  = (const float*)d_in[2];
  const float* W1i  = (const float*)d_in[3];
  const float* b1r  = (const float*)d_in[4];
  const float* b1i  = (const float*)d_in[5];
  const float* t1r  = (const float*)d_in[6];
  const float* t1i  = (const float*)d_in[7];
  const float* eb1r = (const float*)d_in[8];
  const float* eb1i = (const float*)d_in[9];
  const float* W2r  = (const float*)d_in[10];
  const float* W2i  = (const float*)d_in[11];
  const float* b2r  = (const float*)d_in[12];
  const float* b2i  = (const float*)d_in[13];
  const float* t2r  = (const float*)d_in[14];
  const float* t2i  = (const float*)d_in[15];
  const float* eb2r = (const float*)d_in[16];
  const float* eb2i = (const float*)d_in[17];

  const int DIM = 128;
  const int N = in_sizes[0] / DIM;   // 100000
  const int E = in_sizes[1] / 2;     // 800000
  const int deg = (2 * E) / N;       // 16

  char* ws = (char*)d_ws;
  size_t off = 0;
  auto alloc = [&](size_t bytes) -> char* {
    char* p = ws + off;
    off += (bytes + 255) & ~(size_t)255;
    return p;
  };
  int* cnt  = (int*)alloc((size_t)N * 4);
  int* nbrs = (int*)alloc((size_t)N * deg * 4);
  float* wsc = (float*)alloc(8 * 4);
  const size_t nH = (size_t)N * DIM;
  unsigned short* h1 = (unsigned short*)alloc(nH * 4);  // interleaved re/im
  unsigned short* h2 = (unsigned short*)alloc(nH * 4);  // interleaved re/im
  (void)ws_size; (void)n_in; (void)out_size;

  hipMemsetAsync(cnt, 0, (size_t)N * 4, stream);
  build_nbrs<<<(E + 255) / 256, 256, 0, stream>>>(ei, E, cnt, nbrs, deg);
  compute_wscal<<<1, 64, 0, stream>>>(t1r, t1i, t2r, t2i, wsc, deg);

  const int gemm_blocks = (N + 127) / 128;
  const int agg_blocks = (N * 16 + 255) / 256;

  gemm_l1<<<gemm_blocks, 512, 0, stream>>>(x, W1r, W1i, b1r, b1i, h1, N);

  if (deg == 16) {
    fused_l2<16><<<gemm_blocks, 512, 0, stream>>>(h1, nbrs, wsc, eb1r, eb1i,
                                                  W2r, W2i, b2r, b2i, h2, N, deg);
    agg_final<16><<<agg_blocks, 256, 0, stream>>>(h2, nbrs, wsc + 4, eb2r,
                                                  (float*)d_out, N, deg);
  } else {
    fused_l2<0><<<gemm_blocks, 512, 0, stream>>>(h1, nbrs, wsc, eb1r, eb1i,
                                                 W2r, W2i, b2r, b2i, h2, N, deg);
    agg_final<0><<<agg_blocks, 256, 0, stream>>>(h2, nbrs, wsc + 4, eb2r,
                                                 (float*)d_out, N, deg);
  }
}

// Round 7
// 323.054 us; speedup vs baseline: 1.1962x; 1.1962x over previous
//
#include <hip/hip_runtime.h>
#include <hip/hip_bf16.h>
#include <stdint.h>

// ---------- types ----------
typedef __attribute__((ext_vector_type(8))) short bf8_t;    // 8 bf16 (4 VGPRs)
typedef __attribute__((ext_vector_type(4))) float f32x4_t;
typedef __attribute__((ext_vector_type(4))) unsigned short us4_t;

#define MFMA_BF16 __builtin_amdgcn_mfma_f32_16x16x32_bf16

__device__ __forceinline__ unsigned short f2bf(float f) {
  union { float f; unsigned u; } x; x.f = f;
  unsigned r = (x.u + 0x7FFFu + ((x.u >> 16) & 1u)) >> 16;
  return (unsigned short)r;
}
__device__ __forceinline__ float bf2f(unsigned short b) {
  union { unsigned u; float f; } x; x.u = ((unsigned)b) << 16;
  return x.f;
}

// Bijective XCD-chunked swizzle (m204): each XCD owns a contiguous slab of
// node-blocks -> neighbor windows stay inside one XCD's L2.
__device__ __forceinline__ int xcd_swizzle(int b, int nwg) {
  const int NX = 8;
  int q = nwg / NX, r = nwg % NX;
  int xcd = b % NX, idx = b / NX;
  int start = (xcd < r) ? xcd * (q + 1) : r * (q + 1) + (xcd - r) * q;
  return start + idx;
}

// ---------- evolution-row scalars: w0, w1 per layer ----------
// A = star K_{1,deg}; G=expm(-iAt) acts as [[cos(rt),-i sin(rt)],[-i sin(rt),cos(rt)]]
// on span{e0,u'}, identity elsewhere; r = sqrt(deg).
__global__ void compute_wscal(const float* t1r, const float* t1i,
                              const float* t2r, const float* t2i,
                              float* wsc, int deg) {
  if (threadIdx.x != 0 || blockIdx.x != 0) return;
  float r = sqrtf((float)deg);
  for (int l = 0; l < 2; ++l) {
    float tr = l ? t2r[0] : t1r[0];
    float ti = l ? t2i[0] : t1i[0];
    float x = r * tr, y = r * ti;
    float cr = cosf(x) * coshf(y), ci = -sinf(x) * sinhf(y);
    float sr = sinf(x) * coshf(y), si = cosf(x) * sinhf(y);
    float a = cr * cr + ci * ci + sr * sr + si * si;
    float b = -2.0f * (ci * sr - cr * si);
    float s2 = fmaxf(a + fabsf(b), 1.0f);
    float s = sqrtf(s2);
    float l0r = cr / s, l0i = ci / s;              // Lt[0,0]
    float l1r = si / (r * s), l1i = -sr / (r * s); // Lt[0,j]
    float q0 = 1.0f - a / s2;                      // Rt[0,0]^2 (real)
    float r0r = (q0 >= 0.0f) ? sqrtf(q0) : 0.0f;
    float r0i = (q0 >= 0.0f) ? 0.0f : sqrtf(-q0);
    float q1 = -b / (r * s2);                      // Rt[0,j]^2 (real)
    float r1r = (q1 >= 0.0f) ? sqrtf(q1) : 0.0f;
    float r1i = (q1 >= 0.0f) ? 0.0f : sqrtf(-q1);
    wsc[l * 4 + 0] = l0r + r0r;  // w0.re
    wsc[l * 4 + 1] = l0i + r0i;  // w0.im
    wsc[l * 4 + 2] = l1r + r1r;  // w1.re (same for all neighbors)
    wsc[l * 4 + 3] = l1i + r1i;  // w1.im
  }
}

// ---------- neighbor-list build: wave-cooperative, one atomic per key-group ----
__device__ __forceinline__ void store_side(int* __restrict__ cnt,
                                           int* __restrict__ nbrs,
                                           int deg, int key, int val) {
  unsigned long long remaining = __ballot(1);
  unsigned long long mymask = 0;
  while (remaining) {
    int lead = __ffsll((long long)remaining) - 1;
    int lkey = __shfl(key, lead);
    unsigned long long m = __ballot(key == lkey);
    if (key == lkey) mymask = m;
    remaining &= ~m;
  }
  const int lane = threadIdx.x & 63;
  const int leader = __ffsll((long long)mymask) - 1;
  int base = 0;
  if (lane == leader) base = atomicAdd(&cnt[key], __popcll(mymask));
  base = __shfl(base, leader);
  const int rank = __popcll(mymask & ((1ull << lane) - 1ull));
  nbrs[(long)key * deg + base + rank] = val;
}

__global__ __launch_bounds__(256) void build_nbrs(
    const int* __restrict__ ei, int E, int* __restrict__ cnt,
    int* __restrict__ nbrs, int deg) {
  int e = blockIdx.x * 256 + threadIdx.x;
  if (e >= E) return;
  int s = ei[e], d = ei[E + e];
  store_side(cnt, nbrs, deg, s, d);
  store_side(cnt, nbrs, deg, d, s);
}

// ---------- single-plane W staging: f32 global -> bf16 swizzled LDS (32 KB) ----
// byte ^= ((c&7)<<4) breaks the stride-256B bank conflict on ds_read_b128.
__device__ __forceinline__ void stage_w_plane(unsigned char* ldsW,
                                              const float* __restrict__ src,
                                              int tid) {
#pragma unroll
  for (int i = 0; i < 4; ++i) {
    const int e8 = (i * 512 + tid) * 8;             // 8 consecutive f32
    float4 a = *(const float4*)(src + e8);
    float4 b = *(const float4*)(src + e8 + 4);
    union { bf8_t v; unsigned short s[8]; } o;
    o.s[0] = f2bf(a.x); o.s[1] = f2bf(a.y); o.s[2] = f2bf(a.z); o.s[3] = f2bf(a.w);
    o.s[4] = f2bf(b.x); o.s[5] = f2bf(b.y); o.s[6] = f2bf(b.z); o.s[7] = f2bf(b.w);
    const int c = e8 >> 7, k = e8 & 127;
    const int byte = c * 256 + ((k * 2) ^ ((c & 7) << 4));
    *(bf8_t*)(ldsW + byte) = o.v;
  }
}

// Interleaved hidden-state layout: per node 256 us (512 B):
//   chunk g in [0,16): bytes [g*32 .. +15] = re[g*8..+7], [g*32+16 .. +31] = im.
// LDS window rows use byte ^= ((slot&7)<<4) swizzle (writer and reader agree).

// ---------- layer-1 GEMM: h1 = crelu(x @ W1^T + b1), real f32 input ----------
__global__ __launch_bounds__(512, 4) void gemm_l1(
    const float* __restrict__ Xf,
    const float* __restrict__ Wr, const float* __restrict__ Wi,
    const float* __restrict__ br, const float* __restrict__ bi,
    unsigned short* __restrict__ H1, int n) {
  __shared__ unsigned char ldsW[32768];
  const int tid = threadIdx.x;
  const int wv = tid >> 6, lane = tid & 63;
  const int fr = lane & 15, kg = lane >> 4;
  const int lb = xcd_swizzle(blockIdx.x, gridDim.x);
  const int rowbase = lb * 128 + wv * 16;
  const int node = min(rowbase + fr, n - 1);
  const long a_off = (long)node * 128;

  stage_w_plane(ldsW, Wr, tid);                     // pass 1: Wr

  bf8_t a[4];
#pragma unroll
  for (int ks = 0; ks < 4; ++ks) {
    const int koff = ks * 32 + kg * 8;
    float4 u = *(const float4*)(Xf + a_off + koff);
    float4 v = *(const float4*)(Xf + a_off + koff + 4);
    union { bf8_t vv; unsigned short s[8]; } t;
    t.s[0] = f2bf(u.x); t.s[1] = f2bf(u.y); t.s[2] = f2bf(u.z); t.s[3] = f2bf(u.w);
    t.s[4] = f2bf(v.x); t.s[5] = f2bf(v.y); t.s[6] = f2bf(v.z); t.s[7] = f2bf(v.w);
    a[ks] = t.vv;
  }
  __syncthreads();

  f32x4_t accr[8], acci[8];
#pragma unroll
  for (int i = 0; i < 8; ++i) { accr[i] = (f32x4_t)0.0f; acci[i] = (f32x4_t)0.0f; }

#pragma unroll
  for (int cf = 0; cf < 8; ++cf) {
    const int c = cf * 16 + fr;
    const int cbyte = c * 256, swz = (c & 7) << 4;
#pragma unroll
    for (int ks = 0; ks < 4; ++ks) {
      const int kb = (ks * 32 + kg * 8) * 2;
      bf8_t w = *(const bf8_t*)(ldsW + cbyte + (kb ^ swz));
      accr[cf] = MFMA_BF16(w, a[ks], accr[cf], 0, 0, 0);
    }
  }
  __syncthreads();
  stage_w_plane(ldsW, Wi, tid);                     // pass 2: Wi
  __syncthreads();
#pragma unroll
  for (int cf = 0; cf < 8; ++cf) {
    const int c = cf * 16 + fr;
    const int cbyte = c * 256, swz = (c & 7) << 4;
#pragma unroll
    for (int ks = 0; ks < 4; ++ks) {
      const int kb = (ks * 32 + kg * 8) * 2;
      bf8_t w = *(const bf8_t*)(ldsW + cbyte + (kb ^ swz));
      acci[cf] = MFMA_BF16(w, a[ks], acci[cf], 0, 0, 0);
    }
  }

  const int onode = rowbase + fr;
  if (onode < n) {
    const long obase = (long)onode * 256;
#pragma unroll
    for (int cf = 0; cf < 8; ++cf) {
      const int cb = cf * 16 + kg * 4;
      const int chunk = cb >> 3, sub = cb & 7;
      union { float4 f4; float f[4]; } b4r, b4i;
      b4r.f4 = *(const float4*)(br + cb);
      b4i.f4 = *(const float4*)(bi + cb);
      us4_t pr, pi;
#pragma unroll
      for (int j = 0; j < 4; ++j) {
        pr[j] = f2bf(fmaxf(accr[cf][j] + b4r.f[j], 0.0f));
        pi[j] = f2bf(fmaxf(acci[cf][j] + b4i.f[j], 0.0f));
      }
      *(us4_t*)(H1 + obase + chunk * 16 + sub) = pr;
      *(us4_t*)(H1 + obase + chunk * 16 + 8 + sub) = pi;
    }
  }
}

// ---------- fused layer-1 aggregation + layer-2 GEMM + crelu ----------
// Window mode: stage H1 rows [blockstart-8, blockstart+136) into LDS once;
// all neighbor gathers become conflict-free LDS reads. Per-block uniform
// fallback to global gathers keeps any-graph correctness.
#define FWIN 144
template <int DEG>
__global__ __launch_bounds__(512, 2) void fused_l2(
    const unsigned short* __restrict__ H1,
    const int* __restrict__ nbrs, const float* __restrict__ wsc,
    const float* __restrict__ eb1r, const float* __restrict__ eb1i,
    const float* __restrict__ W2r, const float* __restrict__ W2i,
    const float* __restrict__ b2r, const float* __restrict__ b2i,
    unsigned short* __restrict__ H2, int n, int deg_rt) {
  __shared__ unsigned char ldsW[32768];
  __shared__ __align__(16) unsigned char ldsWin[FWIN * 512];
  __shared__ int ldsNB[128 * 17];
  __shared__ int ldsFlag;
  const int tid = threadIdx.x;
  const int wv = tid >> 6, lane = tid & 63;
  const int fr = lane & 15, kg = lane >> 4;
  const int lb = xcd_swizzle(blockIdx.x, gridDim.x);
  const int blockstart = lb * 128;
  const int rowbase = blockstart + wv * 16;
  const int node = min(rowbase + fr, n - 1);
  const int nloc = wv * 16 + fr;
  const int winstart = blockstart - 8;
  const float w0r = wsc[0], w0i = wsc[1], w1r = wsc[2], w1i = wsc[3];
  const int deg = DEG ? DEG : deg_rt;

  if (tid == 0) ldsFlag = (winstart >= 0 && winstart + FWIN <= n) ? 1 : 0;
  __syncthreads();

  if (DEG) {
    // stage nb lists (coalesced, clamped) + in-window check
    const long base = (long)blockstart * deg;
    const long lim = (long)n * deg;
    for (int i = tid; i < 128 * DEG; i += 512) {
      long gidx = base + i;
      int v = (gidx < lim) ? nbrs[gidx] : 0;
      v = min(max(v, 0), n - 1);
      ldsNB[(i / DEG) * 17 + (i % DEG)] = v;
      if ((unsigned)(v - winstart) >= (unsigned)FWIN) ldsFlag = 0;
    }
    // stage H1 window: 144 rows x 32 16B-units, swizzled
    for (int u = tid; u < FWIN * 32; u += 512) {
      const int row = u >> 5, off16 = u & 31;
      const int grow = min(max(winstart + row, 0), n - 1);
      bf8_t v = *(const bf8_t*)(H1 + (long)grow * 256 + off16 * 8);
      *(bf8_t*)(ldsWin + row * 512 + ((off16 * 16) ^ ((row & 7) << 4))) = v;
    }
  }
  stage_w_plane(ldsW, W2r, tid);                    // pass 1: Wr
  __syncthreads();
  const bool fast = DEG && ldsFlag;

  // ---- gather + aggregate -> bf16 A-fragments (gr in ar[], gi in ai[]) ----
  bf8_t ar[4], ai[4];
#pragma unroll
  for (int ks = 0; ks < 4; ++ks) {
    const int ch32 = (ks * 4 + kg) * 32;            // byte offset of chunk
    union { bf8_t v; unsigned short s[8]; } o_r, o_i;
    float sr[8], si[8];
#pragma unroll
    for (int e = 0; e < 8; ++e) { sr[e] = 0.0f; si[e] = 0.0f; }
    if (fast) {
      const int s0 = nloc + 8, sw0 = (s0 & 7) << 4;
      o_r.v = *(const bf8_t*)(ldsWin + s0 * 512 + (ch32 ^ sw0));
      o_i.v = *(const bf8_t*)(ldsWin + s0 * 512 + ((ch32 | 16) ^ sw0));
#pragma unroll
      for (int j = 0; j < (DEG ? DEG : 1); ++j) {
        const int slot = ldsNB[nloc * 17 + j] - winstart;
        const unsigned char* p = ldsWin + slot * 512;
        const int sw = (slot & 7) << 4;
        union { bf8_t v; unsigned short s[8]; } vr2, vi2;
        vr2.v = *(const bf8_t*)(p + (ch32 ^ sw));
        vi2.v = *(const bf8_t*)(p + ((ch32 | 16) ^ sw));
#pragma unroll
        for (int e = 0; e < 8; ++e) { sr[e] += bf2f(vr2.s[e]); si[e] += bf2f(vi2.s[e]); }
      }
    } else {
      const int ch16 = ch32 >> 1;
      o_r.v = *(const bf8_t*)(H1 + (long)node * 256 + ch16);
      o_i.v = *(const bf8_t*)(H1 + (long)node * 256 + ch16 + 8);
      const int* nbp = nbrs + (long)node * deg;
      for (int j = 0; j < deg; ++j) {
        const int v = DEG ? ldsNB[nloc * 17 + j] : min(max(nbp[j], 0), n - 1);
        const long m = (long)v * 256 + ch16;
        union { bf8_t v; unsigned short s[8]; } vr2, vi2;
        vr2.v = *(const bf8_t*)(H1 + m);
        vi2.v = *(const bf8_t*)(H1 + m + 8);
#pragma unroll
        for (int e = 0; e < 8; ++e) { sr[e] += bf2f(vr2.s[e]); si[e] += bf2f(vi2.s[e]); }
      }
    }
    const int koff = ks * 32 + kg * 8;
    union { float4 f4; float f[4]; } er0, er1, ei0, ei1;
    er0.f4 = *(const float4*)(eb1r + koff);
    er1.f4 = *(const float4*)(eb1r + koff + 4);
    ei0.f4 = *(const float4*)(eb1i + koff);
    ei1.f4 = *(const float4*)(eb1i + koff + 4);
    union { bf8_t v; unsigned short s[8]; } pr, pi;
#pragma unroll
    for (int e = 0; e < 8; ++e) {
      float hr = bf2f(o_r.s[e]), hi = bf2f(o_i.s[e]);
      float ebR = (e < 4) ? er0.f[e] : er1.f[e - 4];
      float ebI = (e < 4) ? ei0.f[e] : ei1.f[e - 4];
      float gr = w0r * hr - w0i * hi + w1r * sr[e] - w1i * si[e] + ebR;
      float gi = w0r * hi + w0i * hr + w1r * si[e] + w1i * sr[e] + ebI;
      pr.s[e] = f2bf(gr); pi.s[e] = f2bf(gi);
    }
    ar[ks] = pr.v; ai[ks] = pi.v;
  }

  f32x4_t accr[8], acci[8];
#pragma unroll
  for (int i = 0; i < 8; ++i) { accr[i] = (f32x4_t)0.0f; acci[i] = (f32x4_t)0.0f; }

  // pass 1 (Wr): accr += Wr*gr ; acci += Wr*gi
#pragma unroll
  for (int cf = 0; cf < 8; ++cf) {
    const int c = cf * 16 + fr;
    const int cbyte = c * 256, swz = (c & 7) << 4;
#pragma unroll
    for (int ks = 0; ks < 4; ++ks) {
      const int kb = (ks * 32 + kg * 8) * 2;
      bf8_t w = *(const bf8_t*)(ldsW + cbyte + (kb ^ swz));
      accr[cf] = MFMA_BF16(w, ar[ks], accr[cf], 0, 0, 0);
      acci[cf] = MFMA_BF16(w, ai[ks], acci[cf], 0, 0, 0);
    }
  }
  __syncthreads();
  stage_w_plane(ldsW, W2i, tid);                    // pass 2: Wi
  __syncthreads();

  // negate gi in place
#pragma unroll
  for (int ks = 0; ks < 4; ++ks) {
    union { bf8_t v; unsigned u[4]; } t; t.v = ai[ks];
#pragma unroll
    for (int q = 0; q < 4; ++q) t.u[q] ^= 0x80008000u;
    ai[ks] = t.v;
  }
  // pass 2 (Wi): accr += Wi*(-gi) ; acci += Wi*gr
#pragma unroll
  for (int cf = 0; cf < 8; ++cf) {
    const int c = cf * 16 + fr;
    const int cbyte = c * 256, swz = (c & 7) << 4;
#pragma unroll
    for (int ks = 0; ks < 4; ++ks) {
      const int kb = (ks * 32 + kg * 8) * 2;
      bf8_t w = *(const bf8_t*)(ldsW + cbyte + (kb ^ swz));
      accr[cf] = MFMA_BF16(w, ai[ks], accr[cf], 0, 0, 0);
      acci[cf] = MFMA_BF16(w, ar[ks], acci[cf], 0, 0, 0);
    }
  }

  const int onode = rowbase + fr;
  if (onode < n) {
    const long obase = (long)onode * 256;
#pragma unroll
    for (int cf = 0; cf < 8; ++cf) {
      const int cb = cf * 16 + kg * 4;
      const int chunk = cb >> 3, sub = cb & 7;
      union { float4 f4; float f[4]; } b4r, b4i;
      b4r.f4 = *(const float4*)(b2r + cb);
      b4i.f4 = *(const float4*)(b2i + cb);
      us4_t pr, pi;
#pragma unroll
      for (int j = 0; j < 4; ++j) {
        pr[j] = f2bf(fmaxf(accr[cf][j] + b4r.f[j], 0.0f));
        pi[j] = f2bf(fmaxf(acci[cf][j] + b4i.f[j], 0.0f));
      }
      *(us4_t*)(H2 + obase + chunk * 16 + sub) = pr;
      *(us4_t*)(H2 + obase + chunk * 16 + 8 + sub) = pi;
    }
  }
}

// ---------- final aggregation: out = Re(w0*h + w1*sum_nbr(h) + eb) -------------
// 64 nodes/block, 512 threads, H2 window in LDS; global fallback path.
#define AWIN 80
template <int DEG>
__global__ __launch_bounds__(512, 4) void agg_final(
    const unsigned short* __restrict__ H2,
    const int* __restrict__ nbrs, const float* __restrict__ wsc,
    const float* __restrict__ ebr,
    float* __restrict__ outf, int n, int deg_rt) {
  __shared__ __align__(16) unsigned char ldsWin[AWIN * 512];
  __shared__ int ldsNB[64 * 17];
  __shared__ int ldsFlag;
  const int tid = threadIdx.x;
  const int lb = xcd_swizzle(blockIdx.x, gridDim.x);
  const int blockstart = lb * 64;
  const int winstart = blockstart - 8;
  const int deg = DEG ? DEG : deg_rt;
  const float w0r = wsc[0], w0i = wsc[1], w1r = wsc[2], w1i = wsc[3];

  if (tid == 0) ldsFlag = (winstart >= 0 && winstart + AWIN <= n) ? 1 : 0;
  __syncthreads();
  if (DEG) {
    const long base = (long)blockstart * deg;
    const long lim = (long)n * deg;
    for (int i = tid; i < 64 * DEG; i += 512) {
      long gidx = base + i;
      int v = (gidx < lim) ? nbrs[gidx] : 0;
      v = min(max(v, 0), n - 1);
      ldsNB[(i / DEG) * 17 + (i % DEG)] = v;
      if ((unsigned)(v - winstart) >= (unsigned)AWIN) ldsFlag = 0;
    }
    for (int u = tid; u < AWIN * 32; u += 512) {
      const int row = u >> 5, off16 = u & 31;
      const int grow = min(max(winstart + row, 0), n - 1);
      bf8_t v = *(const bf8_t*)(H2 + (long)grow * 256 + off16 * 8);
      *(bf8_t*)(ldsWin + row * 512 + ((off16 * 16) ^ ((row & 7) << 4))) = v;
    }
  }
  __syncthreads();
  const bool fast = DEG && ldsFlag;

#pragma unroll
  for (int q = 0; q < 2; ++q) {
    const int item = q * 512 + tid;                 // 64 nodes x 16 chunks
    const int nloc = item >> 4, g2 = item & 15;
    const int node = blockstart + nloc;
    const int rnode = min(node, n - 1);
    const int ch32 = g2 * 32;
    union { bf8_t v; unsigned short s[8]; } ur, ui;
    float srf[8], sif[8];
#pragma unroll
    for (int e = 0; e < 8; ++e) { srf[e] = 0.0f; sif[e] = 0.0f; }
    if (fast) {
      const int s0 = nloc + 8, sw0 = (s0 & 7) << 4;
      ur.v = *(const bf8_t*)(ldsWin + s0 * 512 + (ch32 ^ sw0));
      ui.v = *(const bf8_t*)(ldsWin + s0 * 512 + ((ch32 | 16) ^ sw0));
#pragma unroll
      for (int k = 0; k < (DEG ? DEG : 1); ++k) {
        const int slot = ldsNB[nloc * 17 + k] - winstart;
        const unsigned char* p = ldsWin + slot * 512;
        const int sw = (slot & 7) << 4;
        union { bf8_t v; unsigned short s[8]; } vr2, vi2;
        vr2.v = *(const bf8_t*)(p + (ch32 ^ sw));
        vi2.v = *(const bf8_t*)(p + ((ch32 | 16) ^ sw));
#pragma unroll
        for (int e = 0; e < 8; ++e) { srf[e] += bf2f(vr2.s[e]); sif[e] += bf2f(vi2.s[e]); }
      }
    } else {
      const int ch16 = g2 * 16;
      ur.v = *(const bf8_t*)(H2 + (long)rnode * 256 + ch16);
      ui.v = *(const bf8_t*)(H2 + (long)rnode * 256 + ch16 + 8);
      const int* nbp = nbrs + (long)rnode * deg;
      for (int k = 0; k < deg; ++k) {
        const int v = DEG ? ldsNB[nloc * 17 + k] : min(max(nbp[k], 0), n - 1);
        const long m = (long)v * 256 + ch16;
        union { bf8_t v; unsigned short s[8]; } vr2, vi2;
        vr2.v = *(const bf8_t*)(H2 + m);
        vi2.v = *(const bf8_t*)(H2 + m + 8);
#pragma unroll
        for (int e = 0; e < 8; ++e) { srf[e] += bf2f(vr2.s[e]); sif[e] += bf2f(vi2.s[e]); }
      }
    }
    if (node < n) {
      const int ch0 = g2 * 8;
      union { float4 f4; float f[4]; } o0, o1;
#pragma unroll
      for (int e = 0; e < 8; ++e) {
        const int c = ch0 + e;
        float hrf = bf2f(ur.s[e]), hif = bf2f(ui.s[e]);
        float R = w0r * hrf - w0i * hif + w1r * srf[e] - w1i * sif[e] + ebr[c];
        if (e < 4) o0.f[e] = R; else o1.f[e - 4] = R;
      }
      *(float4*)(outf + (long)node * 128 + ch0) = o0.f4;
      *(float4*)(outf + (long)node * 128 + ch0 + 4) = o1.f4;
    }
  }
}

// ---------- launch ----------
extern "C" void kernel_launch(void* const* d_in, const int* in_sizes, int n_in,
                              void* d_out, int out_size, void* d_ws, size_t ws_size,
                              hipStream_t stream) {
  const float* x    = (const float*)d_in[0];
  const int*   ei   = (const int*)d_in[1];
  const float* W1r  = (const float*)d_in[2];
  const float* W1i  = (const float*)d_in[3];
  const float* b1r  = (const float*)d_in[4];
  const float* b1i  = (const float*)d_in[5];
  const float* t1r  = (const float*)d_in[6];
  const float* t1i  = (const float*)d_in[7];
  const float* eb1r = (const float*)d_in[8];
  const float* eb1i = (const float*)d_in[9];
  const float* W2r  = (const float*)d_in[10];
  const float* W2i  = (const float*)d_in[11];
  const float* b2r  = (const float*)d_in[12];
  const float* b2i  = (const float*)d_in[13];
  const float* t2r  = (const float*)d_in[14];
  const float* t2i  = (const float*)d_in[15];
  const float* eb2r = (const float*)d_in[16];
  const float* eb2i = (const float*)d_in[17];

  const int DIM = 128;
  const int N = in_sizes[0] / DIM;   // 100000
  const int E = in_sizes[1] / 2;     // 800000
  const int deg = (2 * E) / N;       // 16

  char* ws = (char*)d_ws;
  size_t off = 0;
  auto alloc = [&](size_t bytes) -> char* {
    char* p = ws + off;
    off += (bytes + 255) & ~(size_t)255;
    return p;
  };
  int* cnt  = (int*)alloc((size_t)N * 4);
  int* nbrs = (int*)alloc((size_t)N * deg * 4);
  float* wsc = (float*)alloc(8 * 4);
  const size_t nH = (size_t)N * DIM;
  unsigned short* h1 = (unsigned short*)alloc(nH * 4);  // interleaved re/im
  unsigned short* h2 = (unsigned short*)alloc(nH * 4);  // interleaved re/im
  (void)ws_size; (void)n_in; (void)out_size;

  hipMemsetAsync(cnt, 0, (size_t)N * 4, stream);
  build_nbrs<<<(E + 255) / 256, 256, 0, stream>>>(ei, E, cnt, nbrs, deg);
  compute_wscal<<<1, 64, 0, stream>>>(t1r, t1i, t2r, t2i, wsc, deg);

  const int gemm_blocks = (N + 127) / 128;
  const int agg_blocks = (N + 63) / 64;

  gemm_l1<<<gemm_blocks, 512, 0, stream>>>(x, W1r, W1i, b1r, b1i, h1, N);

  if (deg == 16) {
    fused_l2<16><<<gemm_blocks, 512, 0, stream>>>(h1, nbrs, wsc, eb1r, eb1i,
                                                  W2r, W2i, b2r, b2i, h2, N, deg);
    agg_final<16><<<agg_blocks, 512, 0, stream>>>(h2, nbrs, wsc + 4, eb2r,
                                                  (float*)d_out, N, deg);
  } else {
    fused_l2<0><<<gemm_blocks, 512, 0, stream>>>(h1, nbrs, wsc, eb1r, eb1i,
                                                 W2r, W2i, b2r, b2i, h2, N, deg);
    agg_final<0><<<agg_blocks, 512, 0, stream>>>(h2, nbrs, wsc + 4, eb2r,
                                                 (float*)d_out, N, deg);
  }
}